// Round 5
// baseline (144.073 us; speedup 1.0000x reference)
//
#include <hip/hip_runtime.h>

typedef short  s4  __attribute__((ext_vector_type(4)));   // 4 bf16 in 2 VGPRs
typedef float  f4  __attribute__((ext_vector_type(4)));
typedef unsigned int u2v __attribute__((ext_vector_type(2)));
typedef unsigned int uint32;
typedef unsigned short ushort16;

#define NF      10
#define CIN     64
#define NTOT    8192              // T*H*W
#define HW      1024
#define FPAD    16                // feature dim padded for MFMA K
#define MSPLIT  16                // m-splits (partials -> reduce kernel)
#define MCHUNK  (NTOT / MSPLIT)   // 512 m per block
#define PSTRIDE 16                // f-stride of partial buffer

// ---- v_mfma_f32_16x16x16_bf16: D[i][j], i=4*(lane/16)+reg (M), j=lane%16 (N)
//      A[i][k]: i=lane%16, k=4*(lane/16)+jj ; B[k][j]: j=lane%16, k=4*(lane/16)+jj
//      D layout == B layout -> relu'd scores feed PV mfma with zero shuffles.
//      Verified empirically R2-R4 (passed, absmax 32 bf16-level).
#if defined(__has_builtin) && __has_builtin(__builtin_amdgcn_mfma_f32_16x16x16bf16_1k)
#define MFMA16(a, b, c) __builtin_amdgcn_mfma_f32_16x16x16bf16_1k((a), (b), (c), 0, 0, 0)
#else
static __device__ inline f4 mfma16_asm(s4 a, s4 b, f4 c) {
    f4 d;
    asm volatile("s_nop 1\n\t"
                 "v_mfma_f32_16x16x16_bf16 %0, %1, %2, %3\n\t"
                 "s_nop 7\n\ts_nop 7"
                 : "=v"(d) : "v"(a), "v"(b), "v"(c));
    return d;
}
#define MFMA16(a, b, c) mfma16_asm((a), (b), (c))
#endif

static __device__ inline ushort16 f32_to_bf16_rne(float x) {
    uint32 u = __builtin_bit_cast(uint32, x);
    u = (u + 0x7fffu + ((u >> 16) & 1u)) >> 16;
    return (ushort16)u;
}

// ---------------------------------------------------------------------------
// Stage 1: projections -> bf16 workspace. Identical to R4.
// ---------------------------------------------------------------------------
__global__ __launch_bounds__(64) void qkv_kernel(
    const float* __restrict__ in1, const float* __restrict__ in2,
    const float* __restrict__ w1, const float* __restrict__ b1,
    const float* __restrict__ w2, const float* __restrict__ b2,
    const float* __restrict__ w3, const float* __restrict__ b3,
    ushort16* __restrict__ qb, ushort16* __restrict__ kb,
    ushort16* __restrict__ vtile)
{
    __shared__ ushort16 lvs[64][FPAD];                 // v staging, 2 KB

    const int tid = threadIdx.x;
    const int n  = blockIdx.x * 64 + tid;
    const int t  = n >> 10;
    const int hw = n & 1023;

    if (blockIdx.y == 0) {
        const float* p = in1 + (size_t)t * (CIN * HW) + hw;
        float a[CIN];
#pragma unroll
        for (int c = 0; c < CIN; ++c) a[c] = p[c * HW];   // 64 loads in flight

        float aq[NF], av[NF];
#pragma unroll
        for (int f = 0; f < NF; ++f) { aq[f] = b1[f]; av[f] = b3[f]; }
#pragma unroll
        for (int c = 0; c < CIN; ++c) {
#pragma unroll
            for (int f = 0; f < NF; ++f) {
                aq[f] = fmaf(w1[f * CIN + c], a[c], aq[f]);
                av[f] = fmaf(w3[f * CIN + c], a[c], av[f]);
            }
        }
        ushort16 row[FPAD];
#pragma unroll
        for (int f = 0; f < NF; ++f) row[f] = f32_to_bf16_rne(aq[f]);
#pragma unroll
        for (int f = NF; f < FPAD; ++f) row[f] = 0;       // K-pad MUST be zero
        ushort16* dq = qb + (size_t)n * FPAD;
        ((uint4*)dq)[0] = ((const uint4*)row)[0];
        ((uint4*)dq)[1] = ((const uint4*)row)[1];

        // v: stage to LDS, then coalesced fragment-order store
#pragma unroll
        for (int f = 0; f < NF; ++f) lvs[tid][f] = f32_to_bf16_rne(av[f]);
#pragma unroll
        for (int f = NF; f < FPAD; ++f) lvs[tid][f] = 0;
        __syncthreads();
        const int quad = (tid & 15) >> 2;
        const int tloc = tid >> 4;
        ushort16 obuf[16];
#pragma unroll
        for (int e = 0; e < 16; ++e) {
            int f  = ((tid & 3) * 4 + (e >> 2)) & 15;
            int mi = quad * 4 + (e & 3);
            obuf[e] = lvs[tloc * 16 + mi][f];
        }
        ushort16* dv = vtile + (size_t)blockIdx.x * 1024 + tid * 16;
        ((uint4*)dv)[0] = ((const uint4*)obuf)[0];
        ((uint4*)dv)[1] = ((const uint4*)obuf)[1];
    } else {
        const float* p = in2 + (size_t)t * (CIN * HW) + hw;
        float a[CIN];
#pragma unroll
        for (int c = 0; c < CIN; ++c) a[c] = p[c * HW];

        float ak[NF];
#pragma unroll
        for (int f = 0; f < NF; ++f) ak[f] = b2[f];
#pragma unroll
        for (int c = 0; c < CIN; ++c) {
#pragma unroll
            for (int f = 0; f < NF; ++f) ak[f] = fmaf(w2[f * CIN + c], a[c], ak[f]);
        }
        ushort16 row[FPAD];
#pragma unroll
        for (int f = 0; f < NF; ++f) row[f] = f32_to_bf16_rne(ak[f]);
#pragma unroll
        for (int f = NF; f < FPAD; ++f) row[f] = 0;
        ushort16* dk = kb + (size_t)n * FPAD;
        ((uint4*)dk)[0] = ((const uint4*)row)[0];
        ((uint4*)dk)[1] = ((const uint4*)row)[1];
    }
}

// ---------------------------------------------------------------------------
// Stage 2: MFMA attention. Identical to R4. Deterministic overwrite of pws
// -> safe to launch multiple times (A/B timing instrumentation this round).
// ---------------------------------------------------------------------------
__global__ __launch_bounds__(256) void attn_mfma_kernel(
    const ushort16* __restrict__ qb, const ushort16* __restrict__ kb,
    const ushort16* __restrict__ vtile, float* __restrict__ pws)
{
    const int lane = threadIdx.x & 63;
    const int wid  = threadIdx.x >> 6;
    const int row  = lane & 15;
    const int quad = lane >> 4;
    const int nb   = blockIdx.x * 256 + wid * 64;      // wave's 64-n base
    const int m0   = blockIdx.y * MCHUNK;

    s4 qf[4];
#pragma unroll
    for (int g = 0; g < 4; ++g)
        qf[g] = *(const s4*)(qb + (size_t)(nb + g * 16 + row) * FPAD + 4 * quad);

    const s4* kp = (const s4*)(kb + (size_t)(m0 + row) * FPAD + 4 * quad);
    const s4* vp = (const s4*)(vtile + (size_t)(m0 >> 4) * 256) + lane;

    f4 acc[4];
#pragma unroll
    for (int g = 0; g < 4; ++g) acc[g] = (f4){0.f, 0.f, 0.f, 0.f};
    const f4 zero = {0.f, 0.f, 0.f, 0.f};

#pragma unroll 4
    for (int s = 0; s < MCHUNK / 16; ++s) {
        s4 kf = kp[s * 64];
        s4 vf = vp[s * 64];
#pragma unroll
        for (int g = 0; g < 4; ++g) {
            f4 sc = MFMA16(kf, qf[g], zero);           // S'[m][nb+16g+row]
            float r0 = fmaxf(sc[0], 0.f), r1 = fmaxf(sc[1], 0.f);
            float r2 = fmaxf(sc[2], 0.f), r3 = fmaxf(sc[3], 0.f);
            uint32 lo = __builtin_amdgcn_perm(__builtin_bit_cast(uint32, r1),
                                              __builtin_bit_cast(uint32, r0), 0x07060302u);
            uint32 hi = __builtin_amdgcn_perm(__builtin_bit_cast(uint32, r3),
                                              __builtin_bit_cast(uint32, r2), 0x07060302u);
            s4 pb = __builtin_bit_cast(s4, (u2v){lo, hi});
            acc[g] = MFMA16(vf, pb, acc[g]);           // out'[f=4q+r][nb+16g+row]
        }
    }

    const int fbase = 4 * quad;
#pragma unroll
    for (int g = 0; g < 4; ++g) {
        const int n = nb + g * 16 + row;
#pragma unroll
        for (int r = 0; r < 4; ++r) {
            int f = fbase + r;
            if (f < NF)
                pws[((size_t)blockIdx.y * PSTRIDE + f) * NTOT + n] = acc[g][r];
        }
    }
}

// ---------------------------------------------------------------------------
// Stage 3: sum MSPLIT partials, write out[t][f][h][w]. Identical to R4.
// ---------------------------------------------------------------------------
__global__ __launch_bounds__(256) void reduce_kernel(
    const float* __restrict__ pws, float* __restrict__ out)
{
    const int gid = blockIdx.x * 256 + threadIdx.x;    // 0 .. NF*NTOT-1
    const int f = gid >> 13;                           // / NTOT
    const int n = gid & (NTOT - 1);
    float s = 0.f;
#pragma unroll
    for (int y = 0; y < MSPLIT; ++y)
        s += pws[((size_t)y * PSTRIDE + f) * NTOT + n];
    const int t = n >> 10, hw = n & 1023;
    out[(size_t)t * (NF * HW) + f * HW + hw] = s;
}

extern "C" void kernel_launch(void* const* d_in, const int* in_sizes, int n_in,
                              void* d_out, int out_size, void* d_ws, size_t ws_size,
                              hipStream_t stream)
{
    const float* in1 = (const float*)d_in[0];
    const float* in2 = (const float*)d_in[1];
    const float* w1  = (const float*)d_in[2];
    const float* b1  = (const float*)d_in[3];
    const float* w2  = (const float*)d_in[4];
    const float* b2  = (const float*)d_in[5];
    const float* w3  = (const float*)d_in[6];
    const float* b3  = (const float*)d_in[7];

    // ws layout: qb | kb | vtile (256 KB each, bf16) | pws (8 MB fp32)
    ushort16* qb    = (ushort16*)d_ws;
    ushort16* kb    = qb + (size_t)NTOT * FPAD;
    ushort16* vtile = kb + (size_t)NTOT * FPAD;
    float*    pws   = (float*)(vtile + (size_t)NTOT * FPAD);
    float*    out   = (float*)d_out;

    qkv_kernel<<<dim3(NTOT / 64, 2), 64, 0, stream>>>(
        in1, in2, w1, b1, w2, b2, w3, b3, qb, kb, vtile);

    // A/B INSTRUMENTATION (this round): attn launched 4x with identical args.
    // Deterministic overwrite -> identical pws. dur_R5 - dur_R4 = 3*attn + gaps.
    attn_mfma_kernel<<<dim3(NTOT / 256, MSPLIT), 256, 0, stream>>>(qb, kb, vtile, pws);
    attn_mfma_kernel<<<dim3(NTOT / 256, MSPLIT), 256, 0, stream>>>(qb, kb, vtile, pws);
    attn_mfma_kernel<<<dim3(NTOT / 256, MSPLIT), 256, 0, stream>>>(qb, kb, vtile, pws);
    attn_mfma_kernel<<<dim3(NTOT / 256, MSPLIT), 256, 0, stream>>>(qb, kb, vtile, pws);

    reduce_kernel<<<dim3(NF * NTOT / 256), 256, 0, stream>>>(pws, out);
}

// Round 6
// 105.648 us; speedup vs baseline: 1.3637x; 1.3637x over previous
//
#include <hip/hip_runtime.h>

typedef short  s4  __attribute__((ext_vector_type(4)));   // 4 bf16 in 2 VGPRs
typedef float  f4  __attribute__((ext_vector_type(4)));
typedef unsigned int u2v __attribute__((ext_vector_type(2)));
typedef unsigned int uint32;
typedef unsigned short ushort16;

#define NF      10
#define CIN     64
#define NTOT    8192              // T*H*W
#define HW      1024
#define FPAD    16                // feature dim padded for MFMA K
#define MSPLIT  32                // m-splits (partials -> reduce kernel)
#define MCHUNK  (NTOT / MSPLIT)   // 256 m per block
#define PSTRIDE 16                // f-stride of partial buffer
#define NT      8                 // 16-n tiles per wave (128 n)

// ---- v_mfma_f32_16x16x16_bf16: D[i][j], i=4*(lane/16)+reg (M), j=lane%16 (N)
//      A[i][k]: i=lane%16, k=4*(lane/16)+jj ; B[k][j]: j=lane%16, k=4*(lane/16)+jj
//      D layout == B layout -> relu'd scores feed PV mfma with zero shuffles.
//      (This D==B k-chunk-of-4 match is unique to the K=16 shape.)
#if defined(__has_builtin) && __has_builtin(__builtin_amdgcn_mfma_f32_16x16x16bf16_1k)
#define MFMA16(a, b, c) __builtin_amdgcn_mfma_f32_16x16x16bf16_1k((a), (b), (c), 0, 0, 0)
#else
static __device__ inline f4 mfma16_asm(s4 a, s4 b, f4 c) {
    f4 d;
    asm volatile("s_nop 1\n\t"
                 "v_mfma_f32_16x16x16_bf16 %0, %1, %2, %3\n\t"
                 "s_nop 7\n\ts_nop 7"
                 : "=v"(d) : "v"(a), "v"(b), "v"(c));
    return d;
}
#define MFMA16(a, b, c) mfma16_asm((a), (b), (c))
#endif

static __device__ inline ushort16 f32_to_bf16_rne(float x) {
    uint32 u = __builtin_bit_cast(uint32, x);
    u = (u + 0x7fffu + ((u >> 16) & 1u)) >> 16;
    return (ushort16)u;
}

// ---------------------------------------------------------------------------
// Stage 1: projections -> bf16 workspace. Identical to R4/R5.
// ---------------------------------------------------------------------------
__global__ __launch_bounds__(64) void qkv_kernel(
    const float* __restrict__ in1, const float* __restrict__ in2,
    const float* __restrict__ w1, const float* __restrict__ b1,
    const float* __restrict__ w2, const float* __restrict__ b2,
    const float* __restrict__ w3, const float* __restrict__ b3,
    ushort16* __restrict__ qb, ushort16* __restrict__ kb,
    ushort16* __restrict__ vtile)
{
    __shared__ ushort16 lvs[64][FPAD];                 // v staging, 2 KB

    const int tid = threadIdx.x;
    const int n  = blockIdx.x * 64 + tid;
    const int t  = n >> 10;
    const int hw = n & 1023;

    if (blockIdx.y == 0) {
        const float* p = in1 + (size_t)t * (CIN * HW) + hw;
        float a[CIN];
#pragma unroll
        for (int c = 0; c < CIN; ++c) a[c] = p[c * HW];   // 64 loads in flight

        float aq[NF], av[NF];
#pragma unroll
        for (int f = 0; f < NF; ++f) { aq[f] = b1[f]; av[f] = b3[f]; }
#pragma unroll
        for (int c = 0; c < CIN; ++c) {
#pragma unroll
            for (int f = 0; f < NF; ++f) {
                aq[f] = fmaf(w1[f * CIN + c], a[c], aq[f]);
                av[f] = fmaf(w3[f * CIN + c], a[c], av[f]);
            }
        }
        ushort16 row[FPAD];
#pragma unroll
        for (int f = 0; f < NF; ++f) row[f] = f32_to_bf16_rne(aq[f]);
#pragma unroll
        for (int f = NF; f < FPAD; ++f) row[f] = 0;       // K-pad MUST be zero
        ushort16* dq = qb + (size_t)n * FPAD;
        ((uint4*)dq)[0] = ((const uint4*)row)[0];
        ((uint4*)dq)[1] = ((const uint4*)row)[1];

        // v: stage to LDS, then coalesced fragment-order store
#pragma unroll
        for (int f = 0; f < NF; ++f) lvs[tid][f] = f32_to_bf16_rne(av[f]);
#pragma unroll
        for (int f = NF; f < FPAD; ++f) lvs[tid][f] = 0;
        __syncthreads();
        const int quad = (tid & 15) >> 2;
        const int tloc = tid >> 4;
        ushort16 obuf[16];
#pragma unroll
        for (int e = 0; e < 16; ++e) {
            int f  = ((tid & 3) * 4 + (e >> 2)) & 15;
            int mi = quad * 4 + (e & 3);
            obuf[e] = lvs[tloc * 16 + mi][f];
        }
        ushort16* dv = vtile + (size_t)blockIdx.x * 1024 + tid * 16;
        ((uint4*)dv)[0] = ((const uint4*)obuf)[0];
        ((uint4*)dv)[1] = ((const uint4*)obuf)[1];
    } else {
        const float* p = in2 + (size_t)t * (CIN * HW) + hw;
        float a[CIN];
#pragma unroll
        for (int c = 0; c < CIN; ++c) a[c] = p[c * HW];

        float ak[NF];
#pragma unroll
        for (int f = 0; f < NF; ++f) ak[f] = b2[f];
#pragma unroll
        for (int c = 0; c < CIN; ++c) {
#pragma unroll
            for (int f = 0; f < NF; ++f) ak[f] = fmaf(w2[f * CIN + c], a[c], ak[f]);
        }
        ushort16 row[FPAD];
#pragma unroll
        for (int f = 0; f < NF; ++f) row[f] = f32_to_bf16_rne(ak[f]);
#pragma unroll
        for (int f = NF; f < FPAD; ++f) row[f] = 0;
        ushort16* dk = kb + (size_t)n * FPAD;
        ((uint4*)dk)[0] = ((const uint4*)row)[0];
        ((uint4*)dk)[1] = ((const uint4*)row)[1];
    }
}

// ---------------------------------------------------------------------------
// Stage 2: MFMA attention. Each wave owns EIGHT 16-n tiles (128 n): one
// kf/vf load pair feeds 16 MFMAs. Explicit next-step prefetch hides
// load->use latency behind the MFMA/VALU burst. No LDS, no atomics.
// grid (NTOT/512, MSPLIT) = (16,32) = 512 blocks, block 256 (8 waves/CU).
// ---------------------------------------------------------------------------
__global__ __launch_bounds__(256) void attn_mfma_kernel(
    const ushort16* __restrict__ qb, const ushort16* __restrict__ kb,
    const ushort16* __restrict__ vtile, float* __restrict__ pws)
{
    const int lane = threadIdx.x & 63;
    const int wid  = threadIdx.x >> 6;
    const int row  = lane & 15;
    const int quad = lane >> 4;
    const int nb   = blockIdx.x * 512 + wid * (NT * 16);   // wave's 128-n base
    const int m0   = blockIdx.y * MCHUNK;

    // NT loop-invariant Q-frags (B operand)
    s4 qf[NT];
#pragma unroll
    for (int g = 0; g < NT; ++g)
        qf[g] = *(const s4*)(qb + (size_t)(nb + g * 16 + row) * FPAD + 4 * quad);

    // K / V fragment streams: contiguous 512 B per 16-m step
    const s4* kp = (const s4*)(kb + (size_t)(m0 + row) * FPAD + 4 * quad);
    const s4* vp = (const s4*)(vtile + (size_t)(m0 >> 4) * 256) + lane;

    f4 acc[NT];
#pragma unroll
    for (int g = 0; g < NT; ++g) acc[g] = (f4){0.f, 0.f, 0.f, 0.f};
    const f4 zero = {0.f, 0.f, 0.f, 0.f};

    // software-pipelined: prefetch step s+1 while computing step s
    s4 kf = kp[0];
    s4 vf = vp[0];
#pragma unroll 2
    for (int s = 0; s < MCHUNK / 16; ++s) {
        s4 kf_n, vf_n;
        if (s + 1 < MCHUNK / 16) {
            kf_n = kp[(s + 1) * 64];
            vf_n = vp[(s + 1) * 64];
        }
#pragma unroll
        for (int g = 0; g < NT; ++g) {
            f4 sc = MFMA16(kf, qf[g], zero);           // S'[m][nb+16g+row]
            float r0 = fmaxf(sc[0], 0.f), r1 = fmaxf(sc[1], 0.f);
            float r2 = fmaxf(sc[2], 0.f), r3 = fmaxf(sc[3], 0.f);
            uint32 lo = __builtin_amdgcn_perm(__builtin_bit_cast(uint32, r1),
                                              __builtin_bit_cast(uint32, r0), 0x07060302u);
            uint32 hi = __builtin_amdgcn_perm(__builtin_bit_cast(uint32, r3),
                                              __builtin_bit_cast(uint32, r2), 0x07060302u);
            s4 pb = __builtin_bit_cast(s4, (u2v){lo, hi});
            acc[g] = MFMA16(vf, pb, acc[g]);           // out'[f=4q+r][nb+16g+row]
        }
        kf = kf_n;
        vf = vf_n;
    }

    const int fbase = 4 * quad;
#pragma unroll
    for (int g = 0; g < NT; ++g) {
        const int n = nb + g * 16 + row;
#pragma unroll
        for (int r = 0; r < 4; ++r) {
            int f = fbase + r;
            if (f < NF)
                pws[((size_t)blockIdx.y * PSTRIDE + f) * NTOT + n] = acc[g][r];
        }
    }
}

// ---------------------------------------------------------------------------
// Stage 3: sum MSPLIT partials, write out[t][f][h][w]. grid 320 x 256.
// ---------------------------------------------------------------------------
__global__ __launch_bounds__(256) void reduce_kernel(
    const float* __restrict__ pws, float* __restrict__ out)
{
    const int gid = blockIdx.x * 256 + threadIdx.x;    // 0 .. NF*NTOT-1
    const int f = gid >> 13;                           // / NTOT
    const int n = gid & (NTOT - 1);
    float s = 0.f;
#pragma unroll
    for (int y = 0; y < MSPLIT; ++y)
        s += pws[((size_t)y * PSTRIDE + f) * NTOT + n];
    const int t = n >> 10, hw = n & 1023;
    out[(size_t)t * (NF * HW) + f * HW + hw] = s;
}

extern "C" void kernel_launch(void* const* d_in, const int* in_sizes, int n_in,
                              void* d_out, int out_size, void* d_ws, size_t ws_size,
                              hipStream_t stream)
{
    const float* in1 = (const float*)d_in[0];
    const float* in2 = (const float*)d_in[1];
    const float* w1  = (const float*)d_in[2];
    const float* b1  = (const float*)d_in[3];
    const float* w2  = (const float*)d_in[4];
    const float* b2  = (const float*)d_in[5];
    const float* w3  = (const float*)d_in[6];
    const float* b3  = (const float*)d_in[7];

    // ws layout: qb | kb | vtile (256 KB each, bf16) | pws (16 MB fp32)
    ushort16* qb    = (ushort16*)d_ws;
    ushort16* kb    = qb + (size_t)NTOT * FPAD;
    ushort16* vtile = kb + (size_t)NTOT * FPAD;
    float*    pws   = (float*)(vtile + (size_t)NTOT * FPAD);
    float*    out   = (float*)d_out;

    qkv_kernel<<<dim3(NTOT / 64, 2), 64, 0, stream>>>(
        in1, in2, w1, b1, w2, b2, w3, b3, qb, kb, vtile);

    attn_mfma_kernel<<<dim3(NTOT / 512, MSPLIT), 256, 0, stream>>>(qb, kb, vtile, pws);

    reduce_kernel<<<dim3(NF * NTOT / 256), 256, 0, stream>>>(pws, out);
}